// Round 2
// baseline (430.912 us; speedup 1.0000x reference)
//
#include <hip/hip_runtime.h>
#include <hip/hip_bf16.h>

typedef unsigned short ushort_t;
typedef short s16x8 __attribute__((ext_vector_type(8)));
typedef float f32x4 __attribute__((ext_vector_type(4)));

#define MFMA16(a, b, c) __builtin_amdgcn_mfma_f32_16x16x32_bf16((a), (b), (c), 0, 0, 0)

// ---- sizes ----
#define BATCH 16
#define N1 1024
#define C1 256
#define N2 256
#define N3 64

// float -> bf16 bits, round-to-nearest-even (inputs are finite normals)
static __device__ __forceinline__ ushort_t f2b(float f) {
    unsigned int u = __builtin_bit_cast(unsigned int, f);
    unsigned int r = (u + 0x7fffu + ((u >> 16) & 1u)) >> 16;
    return (ushort_t)r;
}

// convert 8 consecutive floats to a bf16x8 fragment (as shorts)
static __device__ __forceinline__ s16x8 cvt8(const float* p) {
    f32x4 lo = *reinterpret_cast<const f32x4*>(p);
    f32x4 hi = *reinterpret_cast<const f32x4*>(p + 4);
    s16x8 r;
#pragma unroll
    for (int i = 0; i < 4; ++i) {
        r[i]     = (short)f2b(lo[i]);
        r[i + 4] = (short)f2b(hi[i]);
    }
    return r;
}

// ---- transpose + convert weight: wt[d][k] = (bf16) w[k][d] ----
__global__ void k_wt(const float* __restrict__ w, ushort_t* __restrict__ wt, int K, int D) {
    int i = blockIdx.x * 256 + threadIdx.x;
    if (i >= K * D) return;
    int d = i / K, k = i - d * K;
    wt[i] = f2b(w[(size_t)k * D + d]);
}

// ---- projection GEMM: out[M,256] = A[M,K] @ W[K,256] + bias ----
// block = 256 threads (4 waves); each wave: 16 rows x 256 cols (16 col-frags)
__global__ __launch_bounds__(256) void k_proj(
    const float* __restrict__ A, const ushort_t* __restrict__ wt,
    const float* __restrict__ bias, int K,
    ushort_t* __restrict__ xb, float* __restrict__ p1, ushort_t* __restrict__ x1t)
{
    int w = threadIdx.x >> 6;
    int l = threadIdx.x & 63;
    int lr = l & 15, lk = (l >> 4) * 8;
    int rowBase = blockIdx.x * 64 + w * 16;

    f32x4 acc[16] = {};
    const float* arow = A + (size_t)(rowBase + lr) * K + lk;
    for (int kk = 0; kk < K; kk += 32) {
        s16x8 af = cvt8(arow + kk);
#pragma unroll
        for (int t = 0; t < 16; ++t) {
            const ushort_t* bp = wt + (size_t)(t * 16 + lr) * K + kk + lk;
            s16x8 bf = *reinterpret_cast<const s16x8*>(bp);
            acc[t] = MFMA16(af, bf, acc[t]);
        }
    }
    int r0 = rowBase + (l >> 4) * 4;
#pragma unroll
    for (int t = 0; t < 16; ++t) {
        int c = t * 16 + lr;
        float bs = bias[c];
#pragma unroll
        for (int j = 0; j < 4; ++j) {
            int r = r0 + j;
            float v = acc[t][j] + bs;
            size_t idx = (size_t)r * 256 + c;
            xb[idx] = f2b(v);
            if (p1) p1[idx] = v;
            if (x1t) {
                int b = r >> 10, ml = r & 1023;
                x1t[((size_t)b * 256 + c) * 1024 + ml] = f2b(v);
            }
        }
    }
}

// ---- Gram matrix: att[b][n][m] = sum_c x[b][n][c] * x[b][m][c], K = 256 ----
// block = 256 threads; 64x64 tile; wave computes 32x32 (2x2 frags)
__global__ __launch_bounds__(256) void k_xxt(
    const ushort_t* __restrict__ x, float* __restrict__ att, int n)
{
    int b = blockIdx.z;
    int w = threadIdx.x >> 6, l = threadIdx.x & 63;
    int lr = l & 15, lk = (l >> 4) * 8;
    int rowBase = blockIdx.x * 64 + (w >> 1) * 32;
    int colBase = blockIdx.y * 64 + (w & 1) * 32;
    const ushort_t* xb = x + (size_t)b * n * 256;

    f32x4 acc[2][2] = {};
    for (int kk = 0; kk < 256; kk += 32) {
        s16x8 a[2], bb[2];
#pragma unroll
        for (int i = 0; i < 2; ++i)
            a[i] = *reinterpret_cast<const s16x8*>(xb + (size_t)(rowBase + i * 16 + lr) * 256 + kk + lk);
#pragma unroll
        for (int j = 0; j < 2; ++j)
            bb[j] = *reinterpret_cast<const s16x8*>(xb + (size_t)(colBase + j * 16 + lr) * 256 + kk + lk);
#pragma unroll
        for (int i = 0; i < 2; ++i)
#pragma unroll
            for (int j = 0; j < 2; ++j)
                acc[i][j] = MFMA16(a[i], bb[j], acc[i][j]);
    }
    float* ab = att + (size_t)b * n * n;
#pragma unroll
    for (int i = 0; i < 2; ++i)
#pragma unroll
        for (int j = 0; j < 2; ++j)
#pragma unroll
            for (int q = 0; q < 4; ++q) {
                int r = rowBase + i * 16 + (l >> 4) * 4 + q;
                int c = colBase + j * 16 + lr;
                ab[(size_t)r * n + c] = acc[i][j][q];
            }
}

// ---- fused: att1 = x1 x1^T, blend with bilinear(att2), bilinear(att3), sigmoid -> bf16 ----
// 128x128 tile per block; wave = 64x64 (4x4 frags)
__global__ __launch_bounds__(256) void k_att(
    const ushort_t* __restrict__ x1b, const float* __restrict__ att2,
    const float* __restrict__ att3,
    const float* __restrict__ a1p, const float* __restrict__ a2p, const float* __restrict__ a3p,
    ushort_t* __restrict__ att)
{
    int b = blockIdx.z;
    int w = threadIdx.x >> 6, l = threadIdx.x & 63;
    int lr = l & 15, lk = (l >> 4) * 8;
    int rowBase = blockIdx.x * 128 + (w >> 1) * 64;
    int colBase = blockIdx.y * 128 + (w & 1) * 64;
    const ushort_t* xb = x1b + (size_t)b * N1 * C1;

    f32x4 acc[4][4] = {};
    for (int kk = 0; kk < 256; kk += 32) {
        s16x8 a[4], bb[4];
#pragma unroll
        for (int i = 0; i < 4; ++i)
            a[i] = *reinterpret_cast<const s16x8*>(xb + (size_t)(rowBase + i * 16 + lr) * 256 + kk + lk);
#pragma unroll
        for (int j = 0; j < 4; ++j)
            bb[j] = *reinterpret_cast<const s16x8*>(xb + (size_t)(colBase + j * 16 + lr) * 256 + kk + lk);
#pragma unroll
        for (int i = 0; i < 4; ++i)
#pragma unroll
            for (int j = 0; j < 4; ++j)
                acc[i][j] = MFMA16(a[i], bb[j], acc[i][j]);
    }

    float a1 = *a1p, a2 = *a2p, a3 = *a3p;
    const float* A2 = att2 + (size_t)b * N2 * N2;
    const float* A3 = att3 + (size_t)b * N3 * N3;
    ushort_t* ab = att + (size_t)b * N1 * N1;

#pragma unroll
    for (int i = 0; i < 4; ++i)
#pragma unroll
        for (int j = 0; j < 4; ++j)
#pragma unroll
            for (int q = 0; q < 4; ++q) {
                int nn = rowBase + i * 16 + (l >> 4) * 4 + q;
                int mm = colBase + j * 16 + lr;
                // bilinear from att2 (256 -> 1024, factor 4)
                int r2l = nn >> 2, c2l = mm >> 2;
                int r2h = min(r2l + 1, N2 - 1), c2h = min(c2l + 1, N2 - 1);
                float fr2 = (float)(nn & 3) * 0.25f, fc2 = (float)(mm & 3) * 0.25f;
                float v2 =
                    (1.f - fr2) * ((1.f - fc2) * A2[r2l * N2 + c2l] + fc2 * A2[r2l * N2 + c2h]) +
                    fr2 * ((1.f - fc2) * A2[r2h * N2 + c2l] + fc2 * A2[r2h * N2 + c2h]);
                // bilinear from att3 (64 -> 1024, factor 16)
                int r3l = nn >> 4, c3l = mm >> 4;
                int r3h = min(r3l + 1, N3 - 1), c3h = min(c3l + 1, N3 - 1);
                float fr3 = (float)(nn & 15) * 0.0625f, fc3 = (float)(mm & 15) * 0.0625f;
                float v3 =
                    (1.f - fr3) * ((1.f - fc3) * A3[r3l * N3 + c3l] + fc3 * A3[r3l * N3 + c3h]) +
                    fr3 * ((1.f - fc3) * A3[r3h * N3 + c3l] + fc3 * A3[r3h * N3 + c3h]);
                float s = a1 * acc[i][j][q] + a2 * v2 + a3 * v3;
                float sig = 1.f / (1.f + __expf(-s));
                ab[(size_t)nn * N1 + mm] = f2b(sig);
            }
}

// ---- PV: out[b][n][c] = p1[b][n][c] + sum_m att[b][n][m] * x1[b][m][c] ----
// A = att (row-major bf16), B from x1t[b][c][m]
__global__ __launch_bounds__(256) void k_pv(
    const ushort_t* __restrict__ att, const ushort_t* __restrict__ x1t,
    const float* __restrict__ p1, float* __restrict__ out)
{
    int b = blockIdx.z;
    int w = threadIdx.x >> 6, l = threadIdx.x & 63;
    int lr = l & 15, lk = (l >> 4) * 8;
    int rowBase = blockIdx.x * 128 + (w >> 1) * 64;
    int colBase = blockIdx.y * 128 + (w & 1) * 64;
    const ushort_t* ab = att + (size_t)b * N1 * N1;
    const ushort_t* xt = x1t + (size_t)b * C1 * N1;

    f32x4 acc[4][4] = {};
    for (int kk = 0; kk < 1024; kk += 32) {
        s16x8 a[4], bb[4];
#pragma unroll
        for (int i = 0; i < 4; ++i)
            a[i] = *reinterpret_cast<const s16x8*>(ab + (size_t)(rowBase + i * 16 + lr) * N1 + kk + lk);
#pragma unroll
        for (int j = 0; j < 4; ++j)
            bb[j] = *reinterpret_cast<const s16x8*>(xt + (size_t)(colBase + j * 16 + lr) * N1 + kk + lk);
#pragma unroll
        for (int i = 0; i < 4; ++i)
#pragma unroll
            for (int j = 0; j < 4; ++j)
                acc[i][j] = MFMA16(a[i], bb[j], acc[i][j]);
    }
#pragma unroll
    for (int i = 0; i < 4; ++i)
#pragma unroll
        for (int j = 0; j < 4; ++j)
#pragma unroll
            for (int q = 0; q < 4; ++q) {
                int r = rowBase + i * 16 + (l >> 4) * 4 + q;
                int c = colBase + j * 16 + lr;
                size_t idx = ((size_t)b * N1 + r) * C1 + c;
                out[idx] = p1[idx] + acc[i][j][q];
            }
}

extern "C" void kernel_launch(void* const* d_in, const int* in_sizes, int n_in,
                              void* d_out, int out_size, void* d_ws, size_t ws_size,
                              hipStream_t stream) {
    const float* f1 = (const float*)d_in[0];
    const float* f2 = (const float*)d_in[1];
    const float* f3 = (const float*)d_in[2];
    const float* w1 = (const float*)d_in[3];
    const float* b1 = (const float*)d_in[4];
    const float* w2 = (const float*)d_in[5];
    const float* b2 = (const float*)d_in[6];
    const float* w3 = (const float*)d_in[7];
    const float* b3 = (const float*)d_in[8];
    const float* a1 = (const float*)d_in[9];
    const float* a2 = (const float*)d_in[10];
    const float* a3 = (const float*)d_in[11];

    char* ws = (char*)d_ws;
    size_t off = 0;
    auto alloc = [&](size_t bytes) -> void* {
        void* p = ws + off;
        off += (bytes + 255) & ~(size_t)255;
        return p;
    };
    ushort_t* w1t = (ushort_t*)alloc((size_t)256 * 256 * 2);
    ushort_t* w2t = (ushort_t*)alloc((size_t)256 * 512 * 2);
    ushort_t* w3t = (ushort_t*)alloc((size_t)256 * 1024 * 2);
    float*    p1  = (float*)alloc((size_t)BATCH * N1 * C1 * 4);
    ushort_t* x1b = (ushort_t*)alloc((size_t)BATCH * N1 * C1 * 2);
    ushort_t* x1t = (ushort_t*)alloc((size_t)BATCH * N1 * C1 * 2);
    ushort_t* x2b = (ushort_t*)alloc((size_t)BATCH * N2 * C1 * 2);
    ushort_t* x3b = (ushort_t*)alloc((size_t)BATCH * N3 * C1 * 2);
    float*    att2 = (float*)alloc((size_t)BATCH * N2 * N2 * 4);
    float*    att3 = (float*)alloc((size_t)BATCH * N3 * N3 * 4);
    ushort_t* attb = (ushort_t*)alloc((size_t)BATCH * N1 * N1 * 2);

    k_wt<<<(256 * 256 + 255) / 256, 256, 0, stream>>>(w1, w1t, 256, 256);
    k_wt<<<(512 * 256 + 255) / 256, 256, 0, stream>>>(w2, w2t, 512, 256);
    k_wt<<<(1024 * 256 + 255) / 256, 256, 0, stream>>>(w3, w3t, 1024, 256);

    k_proj<<<BATCH * N1 / 64, 256, 0, stream>>>(f1, w1t, b1, 256, x1b, p1, x1t);
    k_proj<<<BATCH * N2 / 64, 256, 0, stream>>>(f2, w2t, b2, 512, x2b, nullptr, nullptr);
    k_proj<<<BATCH * N3 / 64, 256, 0, stream>>>(f3, w3t, b3, 1024, x3b, nullptr, nullptr);

    k_xxt<<<dim3(N2 / 64, N2 / 64, BATCH), 256, 0, stream>>>(x2b, att2, N2);
    k_xxt<<<dim3(1, 1, BATCH), 256, 0, stream>>>(x3b, att3, N3);

    k_att<<<dim3(N1 / 128, N1 / 128, BATCH), 256, 0, stream>>>(x1b, att2, att3, a1, a2, a3, attb);

    k_pv<<<dim3(N1 / 128, C1 / 128, BATCH), 256, 0, stream>>>(attb, x1t, p1, (float*)d_out);
}

// Round 3
// 256.679 us; speedup vs baseline: 1.6788x; 1.6788x over previous
//
#include <hip/hip_runtime.h>

typedef unsigned short ushort_t;
typedef short s16x8 __attribute__((ext_vector_type(8)));
typedef float f32x4 __attribute__((ext_vector_type(4)));

#define MFMA16(a, b, c) __builtin_amdgcn_mfma_f32_16x16x32_bf16((a), (b), (c), 0, 0, 0)

// ---- sizes ----
#define BATCH 16
#define N1 1024
#define C1 256
#define N2 256
#define N3 64
// proj tiles (16 rows each)
#define T1 1024
#define T2 256
#define T3 64

// float -> bf16 bits, round-to-nearest-even
static __device__ __forceinline__ ushort_t f2b(float f) {
    unsigned int u = __builtin_bit_cast(unsigned int, f);
    unsigned int r = (u + 0x7fffu + ((u >> 16) & 1u)) >> 16;
    return (ushort_t)r;
}

static __device__ __forceinline__ s16x8 cvt8(const float* p) {
    f32x4 lo = *reinterpret_cast<const f32x4*>(p);
    f32x4 hi = *reinterpret_cast<const f32x4*>(p + 4);
    s16x8 r;
#pragma unroll
    for (int i = 0; i < 4; ++i) {
        r[i]     = (short)f2b(lo[i]);
        r[i + 4] = (short)f2b(hi[i]);
    }
    return r;
}

// ---- merged transpose+convert of all three weights: wt[d][k] = bf16(w[k][d]) ----
__global__ void k_wt(const float* __restrict__ w1, const float* __restrict__ w2,
                     const float* __restrict__ w3,
                     ushort_t* __restrict__ w1t, ushort_t* __restrict__ w2t,
                     ushort_t* __restrict__ w3t) {
    int i = blockIdx.x * 256 + threadIdx.x;
    if (i < 65536) {                       // w1: 256x256
        int d = i >> 8, k = i & 255;
        w1t[i] = f2b(w1[k * 256 + d]);
    } else if (i < 65536 + 131072) {       // w2: 512x256
        int j = i - 65536;
        int d = j >> 9, k = j & 511;
        w2t[j] = f2b(w2[k * 256 + d]);
    } else if (i < 65536 + 131072 + 262144) { // w3: 1024x256
        int j = i - 65536 - 131072;
        int d = j >> 10, k = j & 1023;
        w3t[j] = f2b(w3[k * 256 + d]);
    }
}

// ---- merged projection GEMM for f1/f2/f3 ----
// block = 256 threads (4 waves); block computes 16 rows x 256 cols.
// wave w: same 16 rows, cols w*64 .. w*64+63 (4 frags), full-K loop.
// f3 tiles placed first (deepest K, fewest blocks -> start earliest).
__global__ __launch_bounds__(256) void k_proj(
    const float* __restrict__ f1, const float* __restrict__ f2,
    const float* __restrict__ f3,
    const ushort_t* __restrict__ w1t, const ushort_t* __restrict__ w2t,
    const ushort_t* __restrict__ w3t,
    const float* __restrict__ b1, const float* __restrict__ b2,
    const float* __restrict__ b3,
    ushort_t* __restrict__ x1b, float* __restrict__ p1, ushort_t* __restrict__ x1t,
    ushort_t* __restrict__ x2b, ushort_t* __restrict__ x3b)
{
    int bid = blockIdx.x;
    const float* A; const ushort_t* wt; const float* bias;
    ushort_t* xb; int K, tile; bool isf1 = false;
    if (bid < T3)            { A = f3; wt = w3t; bias = b3; xb = x3b; K = 1024; tile = bid; }
    else if (bid < T3 + T2)  { A = f2; wt = w2t; bias = b2; xb = x2b; K = 512;  tile = bid - T3; }
    else                     { A = f1; wt = w1t; bias = b1; xb = x1b; K = 256;  tile = bid - T3 - T2; isf1 = true; }

    int w = threadIdx.x >> 6, l = threadIdx.x & 63;
    int lr = l & 15, lk = (l >> 4) * 8;
    int rowBase = tile * 16;

    const float* arow = A + (size_t)(rowBase + lr) * K + lk;
    f32x4 acc[4] = {};
    for (int kk = 0; kk < K; kk += 32) {
        s16x8 af = cvt8(arow + kk);
#pragma unroll
        for (int t = 0; t < 4; ++t) {
            const ushort_t* bp = wt + (size_t)(w * 64 + t * 16 + lr) * K + kk + lk;
            acc[t] = MFMA16(af, *reinterpret_cast<const s16x8*>(bp), acc[t]);
        }
    }
    int r0 = rowBase + (l >> 4) * 4;
#pragma unroll
    for (int t = 0; t < 4; ++t) {
        int c = w * 64 + t * 16 + lr;
        float bs = bias[c];
#pragma unroll
        for (int j = 0; j < 4; ++j) {
            int r = r0 + j;
            float v = acc[t][j] + bs;
            size_t idx = (size_t)r * 256 + c;
            xb[idx] = f2b(v);
            if (isf1) {
                p1[idx] = v;
                int b = r >> 10, ml = r & 1023;
                x1t[((size_t)b * 256 + c) * 1024 + ml] = f2b(v);
            }
        }
    }
}

// ---- merged Gram matrices: att[b][n][m] = sum_c x[b][n][c]*x[b][m][c] ----
// 64x64 tile per block; wave computes 32x32 (2x2 frags). att3 blocks first.
__global__ __launch_bounds__(256) void k_xxt(
    const ushort_t* __restrict__ x2b, const ushort_t* __restrict__ x3b,
    float* __restrict__ att2, float* __restrict__ att3)
{
    int bid = blockIdx.x;
    const ushort_t* x; float* att; int n, b, bx, by;
    if (bid < 16) { x = x3b; att = att3; n = 64; b = bid; bx = 0; by = 0; }
    else {
        int j = bid - 16;
        x = x2b; att = att2; n = 256;
        b = j >> 4; bx = (j & 15) & 3; by = (j & 15) >> 2;
    }
    int w = threadIdx.x >> 6, l = threadIdx.x & 63;
    int lr = l & 15, lk = (l >> 4) * 8;
    int rowBase = bx * 64 + (w >> 1) * 32;
    int colBase = by * 64 + (w & 1) * 32;
    const ushort_t* xb = x + (size_t)b * n * 256;

    f32x4 acc[2][2] = {};
    for (int kk = 0; kk < 256; kk += 32) {
        s16x8 a[2], bb[2];
#pragma unroll
        for (int i = 0; i < 2; ++i)
            a[i] = *reinterpret_cast<const s16x8*>(xb + (size_t)(rowBase + i * 16 + lr) * 256 + kk + lk);
#pragma unroll
        for (int j = 0; j < 2; ++j)
            bb[j] = *reinterpret_cast<const s16x8*>(xb + (size_t)(colBase + j * 16 + lr) * 256 + kk + lk);
#pragma unroll
        for (int i = 0; i < 2; ++i)
#pragma unroll
            for (int j = 0; j < 2; ++j)
                acc[i][j] = MFMA16(a[i], bb[j], acc[i][j]);
    }
    float* ab = att + (size_t)b * n * n;
#pragma unroll
    for (int i = 0; i < 2; ++i)
#pragma unroll
        for (int j = 0; j < 2; ++j)
#pragma unroll
            for (int q = 0; q < 4; ++q) {
                int r = rowBase + i * 16 + (l >> 4) * 4 + q;
                int c = colBase + j * 16 + lr;
                ab[(size_t)r * n + c] = acc[i][j][q];
            }
}

// ---- fused: att1 = x1 x1^T, blend with bilinear(att2), bilinear(att3), sigmoid -> bf16 ----
__global__ __launch_bounds__(256) void k_att(
    const ushort_t* __restrict__ x1b, const float* __restrict__ att2,
    const float* __restrict__ att3,
    const float* __restrict__ a1p, const float* __restrict__ a2p, const float* __restrict__ a3p,
    ushort_t* __restrict__ att)
{
    int b = blockIdx.z;
    int w = threadIdx.x >> 6, l = threadIdx.x & 63;
    int lr = l & 15, lk = (l >> 4) * 8;
    int rowBase = blockIdx.x * 128 + (w >> 1) * 64;
    int colBase = blockIdx.y * 128 + (w & 1) * 64;
    const ushort_t* xb = x1b + (size_t)b * N1 * C1;

    f32x4 acc[4][4] = {};
    for (int kk = 0; kk < 256; kk += 32) {
        s16x8 a[4], bb[4];
#pragma unroll
        for (int i = 0; i < 4; ++i)
            a[i] = *reinterpret_cast<const s16x8*>(xb + (size_t)(rowBase + i * 16 + lr) * 256 + kk + lk);
#pragma unroll
        for (int j = 0; j < 4; ++j)
            bb[j] = *reinterpret_cast<const s16x8*>(xb + (size_t)(colBase + j * 16 + lr) * 256 + kk + lk);
#pragma unroll
        for (int i = 0; i < 4; ++i)
#pragma unroll
            for (int j = 0; j < 4; ++j)
                acc[i][j] = MFMA16(a[i], bb[j], acc[i][j]);
    }

    float a1 = *a1p, a2 = *a2p, a3 = *a3p;
    const float* A2 = att2 + (size_t)b * N2 * N2;
    const float* A3 = att3 + (size_t)b * N3 * N3;
    ushort_t* ab = att + (size_t)b * N1 * N1;

#pragma unroll
    for (int i = 0; i < 4; ++i)
#pragma unroll
        for (int j = 0; j < 4; ++j)
#pragma unroll
            for (int q = 0; q < 4; ++q) {
                int nn = rowBase + i * 16 + (l >> 4) * 4 + q;
                int mm = colBase + j * 16 + lr;
                int r2l = nn >> 2, c2l = mm >> 2;
                int r2h = min(r2l + 1, N2 - 1), c2h = min(c2l + 1, N2 - 1);
                float fr2 = (float)(nn & 3) * 0.25f, fc2 = (float)(mm & 3) * 0.25f;
                float v2 =
                    (1.f - fr2) * ((1.f - fc2) * A2[r2l * N2 + c2l] + fc2 * A2[r2l * N2 + c2h]) +
                    fr2 * ((1.f - fc2) * A2[r2h * N2 + c2l] + fc2 * A2[r2h * N2 + c2h]);
                int r3l = nn >> 4, c3l = mm >> 4;
                int r3h = min(r3l + 1, N3 - 1), c3h = min(c3l + 1, N3 - 1);
                float fr3 = (float)(nn & 15) * 0.0625f, fc3 = (float)(mm & 15) * 0.0625f;
                float v3 =
                    (1.f - fr3) * ((1.f - fc3) * A3[r3l * N3 + c3l] + fc3 * A3[r3l * N3 + c3h]) +
                    fr3 * ((1.f - fc3) * A3[r3h * N3 + c3l] + fc3 * A3[r3h * N3 + c3h]);
                float s = a1 * acc[i][j][q] + a2 * v2 + a3 * v3;
                float sig = 1.f / (1.f + __expf(-s));
                ab[(size_t)nn * N1 + mm] = f2b(sig);
            }
}

// ---- PV: out[b][n][c] = p1[b][n][c] + sum_m att[b][n][m] * x1[b][m][c] ----
__global__ __launch_bounds__(256) void k_pv(
    const ushort_t* __restrict__ att, const ushort_t* __restrict__ x1t,
    const float* __restrict__ p1, float* __restrict__ out)
{
    int b = blockIdx.z;
    int w = threadIdx.x >> 6, l = threadIdx.x & 63;
    int lr = l & 15, lk = (l >> 4) * 8;
    int rowBase = blockIdx.x * 128 + (w >> 1) * 64;
    int colBase = blockIdx.y * 128 + (w & 1) * 64;
    const ushort_t* ab = att + (size_t)b * N1 * N1;
    const ushort_t* xt = x1t + (size_t)b * C1 * N1;

    f32x4 acc[4][4] = {};
    for (int kk = 0; kk < 1024; kk += 32) {
        s16x8 a[4], bb[4];
#pragma unroll
        for (int i = 0; i < 4; ++i)
            a[i] = *reinterpret_cast<const s16x8*>(ab + (size_t)(rowBase + i * 16 + lr) * N1 + kk + lk);
#pragma unroll
        for (int j = 0; j < 4; ++j)
            bb[j] = *reinterpret_cast<const s16x8*>(xt + (size_t)(colBase + j * 16 + lr) * N1 + kk + lk);
#pragma unroll
        for (int i = 0; i < 4; ++i)
#pragma unroll
            for (int j = 0; j < 4; ++j)
                acc[i][j] = MFMA16(a[i], bb[j], acc[i][j]);
    }
#pragma unroll
    for (int i = 0; i < 4; ++i)
#pragma unroll
        for (int j = 0; j < 4; ++j)
#pragma unroll
            for (int q = 0; q < 4; ++q) {
                int r = rowBase + i * 16 + (l >> 4) * 4 + q;
                int c = colBase + j * 16 + lr;
                size_t idx = ((size_t)b * N1 + r) * C1 + c;
                out[idx] = p1[idx] + acc[i][j][q];
            }
}

extern "C" void kernel_launch(void* const* d_in, const int* in_sizes, int n_in,
                              void* d_out, int out_size, void* d_ws, size_t ws_size,
                              hipStream_t stream) {
    const float* f1 = (const float*)d_in[0];
    const float* f2 = (const float*)d_in[1];
    const float* f3 = (const float*)d_in[2];
    const float* w1 = (const float*)d_in[3];
    const float* b1 = (const float*)d_in[4];
    const float* w2 = (const float*)d_in[5];
    const float* b2 = (const float*)d_in[6];
    const float* w3 = (const float*)d_in[7];
    const float* b3 = (const float*)d_in[8];
    const float* a1 = (const float*)d_in[9];
    const float* a2 = (const float*)d_in[10];
    const float* a3 = (const float*)d_in[11];

    char* ws = (char*)d_ws;
    size_t off = 0;
    auto alloc = [&](size_t bytes) -> void* {
        void* p = ws + off;
        off += (bytes + 255) & ~(size_t)255;
        return p;
    };
    ushort_t* w1t = (ushort_t*)alloc((size_t)256 * 256 * 2);
    ushort_t* w2t = (ushort_t*)alloc((size_t)256 * 512 * 2);
    ushort_t* w3t = (ushort_t*)alloc((size_t)256 * 1024 * 2);
    float*    p1  = (float*)alloc((size_t)BATCH * N1 * C1 * 4);
    ushort_t* x1b = (ushort_t*)alloc((size_t)BATCH * N1 * C1 * 2);
    ushort_t* x1t = (ushort_t*)alloc((size_t)BATCH * N1 * C1 * 2);
    ushort_t* x2b = (ushort_t*)alloc((size_t)BATCH * N2 * C1 * 2);
    ushort_t* x3b = (ushort_t*)alloc((size_t)BATCH * N3 * C1 * 2);
    float*    att2 = (float*)alloc((size_t)BATCH * N2 * N2 * 4);
    float*    att3 = (float*)alloc((size_t)BATCH * N3 * N3 * 4);
    ushort_t* attb = (ushort_t*)alloc((size_t)BATCH * N1 * N1 * 2);

    k_wt<<<(65536 + 131072 + 262144 + 255) / 256, 256, 0, stream>>>(w1, w2, w3, w1t, w2t, w3t);

    k_proj<<<T1 + T2 + T3, 256, 0, stream>>>(f1, f2, f3, w1t, w2t, w3t,
                                             b1, b2, b3, x1b, p1, x1t, x2b, x3b);

    k_xxt<<<16 + 256, 256, 0, stream>>>(x2b, x3b, att2, att3);

    k_att<<<dim3(N1 / 128, N1 / 128, BATCH), 256, 0, stream>>>(x1b, att2, att3, a1, a2, a3, attb);

    k_pv<<<dim3(N1 / 128, C1 / 128, BATCH), 256, 0, stream>>>(attb, x1t, p1, (float*)d_out);
}

// Round 4
// 246.962 us; speedup vs baseline: 1.7449x; 1.0393x over previous
//
#include <hip/hip_runtime.h>

typedef unsigned short ushort_t;
typedef short s16x8 __attribute__((ext_vector_type(8)));
typedef float f32x4 __attribute__((ext_vector_type(4)));

#define MFMA16(a, b, c) __builtin_amdgcn_mfma_f32_16x16x32_bf16((a), (b), (c), 0, 0, 0)

// ---- sizes ----
#define BATCH 16
#define N1 1024
#define C1 256
#define N2 256
#define N3 64
// proj block counts: f3 16-row, f2 16-row, f1 64-row
#define PB3 64
#define PB2 256
#define PB1 256
// LDS transpose row stride (ushorts): 72*2=144 B -> 16B aligned, ~2-way bank conflict (free)
#define TSTRIDE 72

// float -> bf16 bits, round-to-nearest-even
static __device__ __forceinline__ ushort_t f2b(float f) {
    unsigned int u = __builtin_bit_cast(unsigned int, f);
    unsigned int r = (u + 0x7fffu + ((u >> 16) & 1u)) >> 16;
    return (ushort_t)r;
}
static __device__ __forceinline__ float b2f(ushort_t b) {
    unsigned int u = ((unsigned int)b) << 16;
    return __builtin_bit_cast(float, u);
}

static __device__ __forceinline__ s16x8 cvt8(const float* p) {
    f32x4 lo = *reinterpret_cast<const f32x4*>(p);
    f32x4 hi = *reinterpret_cast<const f32x4*>(p + 4);
    s16x8 r;
#pragma unroll
    for (int i = 0; i < 4; ++i) {
        r[i]     = (short)f2b(lo[i]);
        r[i + 4] = (short)f2b(hi[i]);
    }
    return r;
}

// ---- merged transpose+convert of all three weights: wt[d][k] = bf16(w[k][d]) ----
__global__ void k_wt(const float* __restrict__ w1, const float* __restrict__ w2,
                     const float* __restrict__ w3,
                     ushort_t* __restrict__ w1t, ushort_t* __restrict__ w2t,
                     ushort_t* __restrict__ w3t) {
    int i = blockIdx.x * 256 + threadIdx.x;
    if (i < 65536) {
        int d = i >> 8, k = i & 255;
        w1t[i] = f2b(w1[k * 256 + d]);
    } else if (i < 65536 + 131072) {
        int j = i - 65536;
        int d = j >> 9, k = j & 511;
        w2t[j] = f2b(w2[k * 256 + d]);
    } else if (i < 65536 + 131072 + 262144) {
        int j = i - 65536 - 131072;
        int d = j >> 10, k = j & 1023;
        w3t[j] = f2b(w3[k * 256 + d]);
    }
}

// ---- merged projection GEMM ----
// f3: 16-row blocks [0, PB3); f2: 16-row blocks [PB3, PB3+PB2);
// f1: 64-row blocks [PB3+PB2, PB3+PB2+PB1) with LDS-transposed x1t write.
__global__ __launch_bounds__(256) void k_proj(
    const float* __restrict__ f1, const float* __restrict__ f2,
    const float* __restrict__ f3,
    const ushort_t* __restrict__ w1t, const ushort_t* __restrict__ w2t,
    const ushort_t* __restrict__ w3t,
    const float* __restrict__ b1, const float* __restrict__ b2,
    const float* __restrict__ b3,
    ushort_t* __restrict__ x1b, ushort_t* __restrict__ x1t,
    ushort_t* __restrict__ x2b, ushort_t* __restrict__ x3b)
{
    __shared__ ushort_t sT[256 * TSTRIDE];  // 36.9 KB, used by f1 path only

    int bid = blockIdx.x;
    int w = threadIdx.x >> 6, l = threadIdx.x & 63;
    int lr = l & 15, lk = (l >> 4) * 8;

    if (bid < PB3 + PB2) {
        // ---- f2 / f3: 16 rows x 256 cols per block; wave w covers cols w*64..+64 ----
        const float* A; const ushort_t* wt; const float* bias; ushort_t* xb; int K, tile;
        if (bid < PB3) { A = f3; wt = w3t; bias = b3; xb = x3b; K = 1024; tile = bid; }
        else           { A = f2; wt = w2t; bias = b2; xb = x2b; K = 512;  tile = bid - PB3; }
        int rowBase = tile * 16;

        const float* arow = A + (size_t)(rowBase + lr) * K + lk;
        f32x4 acc[4] = {};
        for (int kk = 0; kk < K; kk += 32) {
            s16x8 af = cvt8(arow + kk);
#pragma unroll
            for (int t = 0; t < 4; ++t) {
                const ushort_t* bp = wt + (size_t)(w * 64 + t * 16 + lr) * K + kk + lk;
                acc[t] = MFMA16(af, *reinterpret_cast<const s16x8*>(bp), acc[t]);
            }
        }
        int r0 = rowBase + (l >> 4) * 4;
#pragma unroll
        for (int t = 0; t < 4; ++t) {
            int c = w * 64 + t * 16 + lr;
            float bs = bias[c];
#pragma unroll
            for (int j = 0; j < 4; ++j) {
                float v = acc[t][j] + bs;
                xb[(size_t)(r0 + j) * 256 + c] = f2b(v);
            }
        }
    } else {
        // ---- f1: 64 rows x 256 cols per block; wave w covers rows w*16..+16, all cols ----
        int tile = bid - PB3 - PB2;
        int rowBase = tile * 64;
        const float* arow = f1 + (size_t)(rowBase + w * 16 + lr) * 256 + lk;

        f32x4 acc[16] = {};
        for (int kk = 0; kk < 256; kk += 32) {
            s16x8 af = cvt8(arow + kk);
#pragma unroll
            for (int t = 0; t < 16; ++t) {
                const ushort_t* bp = w1t + (size_t)(t * 16 + lr) * 256 + kk + lk;
                acc[t] = MFMA16(af, *reinterpret_cast<const s16x8*>(bp), acc[t]);
            }
        }
        int rl0 = w * 16 + (l >> 4) * 4;     // local row 0..63
        int r0 = rowBase + rl0;
#pragma unroll
        for (int t = 0; t < 16; ++t) {
            int c = t * 16 + lr;
            float bs = b1[c];
#pragma unroll
            for (int j = 0; j < 4; ++j) {
                float v = acc[t][j] + bs;
                ushort_t bits = f2b(v);
                x1b[(size_t)(r0 + j) * 256 + c] = bits;
                sT[c * TSTRIDE + rl0 + j] = bits;
            }
        }
        __syncthreads();
        // coalesced x1t write: 4 iters, thread t covers row c = it*64 + (t>>2), 32B chunk q = t&3
        int b = rowBase >> 10;
        int mBase = rowBase & 1023;
        int q = threadIdx.x & 3;
#pragma unroll
        for (int it = 0; it < 4; ++it) {
            int c = it * 64 + (threadIdx.x >> 2);
            const uint4* src = reinterpret_cast<const uint4*>(&sT[c * TSTRIDE + q * 16]);
            uint4* dst = reinterpret_cast<uint4*>(&x1t[((size_t)b * 256 + c) * 1024 + mBase + q * 16]);
            dst[0] = src[0];
            dst[1] = src[1];
        }
    }
}

// ---- merged Gram matrices ----
__global__ __launch_bounds__(256) void k_xxt(
    const ushort_t* __restrict__ x2b, const ushort_t* __restrict__ x3b,
    float* __restrict__ att2, float* __restrict__ att3)
{
    int bid = blockIdx.x;
    const ushort_t* x; float* att; int n, b, bx, by;
    if (bid < 16) { x = x3b; att = att3; n = 64; b = bid; bx = 0; by = 0; }
    else {
        int j = bid - 16;
        x = x2b; att = att2; n = 256;
        b = j >> 4; bx = (j & 15) & 3; by = (j & 15) >> 2;
    }
    int w = threadIdx.x >> 6, l = threadIdx.x & 63;
    int lr = l & 15, lk = (l >> 4) * 8;
    int rowBase = bx * 64 + (w >> 1) * 32;
    int colBase = by * 64 + (w & 1) * 32;
    const ushort_t* xb = x + (size_t)b * n * 256;

    f32x4 acc[2][2] = {};
    for (int kk = 0; kk < 256; kk += 32) {
        s16x8 a[2], bb[2];
#pragma unroll
        for (int i = 0; i < 2; ++i)
            a[i] = *reinterpret_cast<const s16x8*>(xb + (size_t)(rowBase + i * 16 + lr) * 256 + kk + lk);
#pragma unroll
        for (int j = 0; j < 2; ++j)
            bb[j] = *reinterpret_cast<const s16x8*>(xb + (size_t)(colBase + j * 16 + lr) * 256 + kk + lk);
#pragma unroll
        for (int i = 0; i < 2; ++i)
#pragma unroll
            for (int j = 0; j < 2; ++j)
                acc[i][j] = MFMA16(a[i], bb[j], acc[i][j]);
    }
    float* ab = att + (size_t)b * n * n;
#pragma unroll
    for (int i = 0; i < 2; ++i)
#pragma unroll
        for (int j = 0; j < 2; ++j)
#pragma unroll
            for (int q = 0; q < 4; ++q) {
                int r = rowBase + i * 16 + (l >> 4) * 4 + q;
                int c = colBase + j * 16 + lr;
                ab[(size_t)r * n + c] = acc[i][j][q];
            }
}

// ---- fused att assembly: att1 MFMA + bilinear(att2,att3) + sigmoid -> bf16 ----
__global__ __launch_bounds__(256) void k_att(
    const ushort_t* __restrict__ x1b, const float* __restrict__ att2,
    const float* __restrict__ att3,
    const float* __restrict__ a1p, const float* __restrict__ a2p, const float* __restrict__ a3p,
    ushort_t* __restrict__ att)
{
    int b = blockIdx.z;
    int w = threadIdx.x >> 6, l = threadIdx.x & 63;
    int lr = l & 15, lk = (l >> 4) * 8;
    int rowBase = blockIdx.x * 128 + (w >> 1) * 64;
    int colBase = blockIdx.y * 128 + (w & 1) * 64;
    const ushort_t* xb = x1b + (size_t)b * N1 * C1;

    f32x4 acc[4][4] = {};
    for (int kk = 0; kk < 256; kk += 32) {
        s16x8 a[4], bb[4];
#pragma unroll
        for (int i = 0; i < 4; ++i)
            a[i] = *reinterpret_cast<const s16x8*>(xb + (size_t)(rowBase + i * 16 + lr) * 256 + kk + lk);
#pragma unroll
        for (int j = 0; j < 4; ++j)
            bb[j] = *reinterpret_cast<const s16x8*>(xb + (size_t)(colBase + j * 16 + lr) * 256 + kk + lk);
#pragma unroll
        for (int i = 0; i < 4; ++i)
#pragma unroll
            for (int j = 0; j < 4; ++j)
                acc[i][j] = MFMA16(a[i], bb[j], acc[i][j]);
    }

    float a1 = *a1p, a2 = *a2p, a3 = *a3p;
    const float* A2 = att2 + (size_t)b * N2 * N2;
    const float* A3 = att3 + (size_t)b * N3 * N3;
    ushort_t* ab = att + (size_t)b * N1 * N1;

#pragma unroll
    for (int i = 0; i < 4; ++i)
#pragma unroll
        for (int j = 0; j < 4; ++j)
#pragma unroll
            for (int q = 0; q < 4; ++q) {
                int nn = rowBase + i * 16 + (l >> 4) * 4 + q;
                int mm = colBase + j * 16 + lr;
                int r2l = nn >> 2, c2l = mm >> 2;
                int r2h = min(r2l + 1, N2 - 1), c2h = min(c2l + 1, N2 - 1);
                float fr2 = (float)(nn & 3) * 0.25f, fc2 = (float)(mm & 3) * 0.25f;
                float v2 =
                    (1.f - fr2) * ((1.f - fc2) * A2[r2l * N2 + c2l] + fc2 * A2[r2l * N2 + c2h]) +
                    fr2 * ((1.f - fc2) * A2[r2h * N2 + c2l] + fc2 * A2[r2h * N2 + c2h]);
                int r3l = nn >> 4, c3l = mm >> 4;
                int r3h = min(r3l + 1, N3 - 1), c3h = min(c3l + 1, N3 - 1);
                float fr3 = (float)(nn & 15) * 0.0625f, fc3 = (float)(mm & 15) * 0.0625f;
                float v3 =
                    (1.f - fr3) * ((1.f - fc3) * A3[r3l * N3 + c3l] + fc3 * A3[r3l * N3 + c3h]) +
                    fr3 * ((1.f - fc3) * A3[r3h * N3 + c3l] + fc3 * A3[r3h * N3 + c3h]);
                float s = a1 * acc[i][j][q] + a2 * v2 + a3 * v3;
                float sig = 1.f / (1.f + __expf(-s));
                ab[(size_t)nn * N1 + mm] = f2b(sig);
            }
}

// ---- PV: out[b][n][c] = bf16(x1b)[b][n][c] + sum_m att[b][n][m] * x1[b][m][c] ----
__global__ __launch_bounds__(256) void k_pv(
    const ushort_t* __restrict__ att, const ushort_t* __restrict__ x1t,
    const ushort_t* __restrict__ x1b, float* __restrict__ out)
{
    int b = blockIdx.z;
    int w = threadIdx.x >> 6, l = threadIdx.x & 63;
    int lr = l & 15, lk = (l >> 4) * 8;
    int rowBase = blockIdx.x * 128 + (w >> 1) * 64;
    int colBase = blockIdx.y * 128 + (w & 1) * 64;
    const ushort_t* ab = att + (size_t)b * N1 * N1;
    const ushort_t* xt = x1t + (size_t)b * C1 * N1;

    f32x4 acc[4][4] = {};
    for (int kk = 0; kk < 1024; kk += 32) {
        s16x8 a[4], bb[4];
#pragma unroll
        for (int i = 0; i < 4; ++i)
            a[i] = *reinterpret_cast<const s16x8*>(ab + (size_t)(rowBase + i * 16 + lr) * N1 + kk + lk);
#pragma unroll
        for (int j = 0; j < 4; ++j)
            bb[j] = *reinterpret_cast<const s16x8*>(xt + (size_t)(colBase + j * 16 + lr) * N1 + kk + lk);
#pragma unroll
        for (int i = 0; i < 4; ++i)
#pragma unroll
            for (int j = 0; j < 4; ++j)
                acc[i][j] = MFMA16(a[i], bb[j], acc[i][j]);
    }
#pragma unroll
    for (int i = 0; i < 4; ++i)
#pragma unroll
        for (int j = 0; j < 4; ++j)
#pragma unroll
            for (int q = 0; q < 4; ++q) {
                int r = rowBase + i * 16 + (l >> 4) * 4 + q;
                int c = colBase + j * 16 + lr;
                size_t idx = ((size_t)b * N1 + r) * C1 + c;
                out[idx] = b2f(x1b[idx]) + acc[i][j][q];
            }
}

extern "C" void kernel_launch(void* const* d_in, const int* in_sizes, int n_in,
                              void* d_out, int out_size, void* d_ws, size_t ws_size,
                              hipStream_t stream) {
    const float* f1 = (const float*)d_in[0];
    const float* f2 = (const float*)d_in[1];
    const float* f3 = (const float*)d_in[2];
    const float* w1 = (const float*)d_in[3];
    const float* b1 = (const float*)d_in[4];
    const float* w2 = (const float*)d_in[5];
    const float* b2 = (const float*)d_in[6];
    const float* w3 = (const float*)d_in[7];
    const float* b3 = (const float*)d_in[8];
    const float* a1 = (const float*)d_in[9];
    const float* a2 = (const float*)d_in[10];
    const float* a3 = (const float*)d_in[11];

    char* ws = (char*)d_ws;
    size_t off = 0;
    auto alloc = [&](size_t bytes) -> void* {
        void* p = ws + off;
        off += (bytes + 255) & ~(size_t)255;
        return p;
    };
    ushort_t* w1t = (ushort_t*)alloc((size_t)256 * 256 * 2);
    ushort_t* w2t = (ushort_t*)alloc((size_t)256 * 512 * 2);
    ushort_t* w3t = (ushort_t*)alloc((size_t)256 * 1024 * 2);
    ushort_t* x1b = (ushort_t*)alloc((size_t)BATCH * N1 * C1 * 2);
    ushort_t* x1t = (ushort_t*)alloc((size_t)BATCH * N1 * C1 * 2);
    ushort_t* x2b = (ushort_t*)alloc((size_t)BATCH * N2 * C1 * 2);
    ushort_t* x3b = (ushort_t*)alloc((size_t)BATCH * N3 * C1 * 2);
    float*    att2 = (float*)alloc((size_t)BATCH * N2 * N2 * 4);
    float*    att3 = (float*)alloc((size_t)BATCH * N3 * N3 * 4);
    ushort_t* attb = (ushort_t*)alloc((size_t)BATCH * N1 * N1 * 2);

    k_wt<<<(65536 + 131072 + 262144 + 255) / 256, 256, 0, stream>>>(w1, w2, w3, w1t, w2t, w3t);

    k_proj<<<PB3 + PB2 + PB1, 256, 0, stream>>>(f1, f2, f3, w1t, w2t, w3t,
                                                b1, b2, b3, x1b, x1t, x2b, x3b);

    k_xxt<<<16 + 256, 256, 0, stream>>>(x2b, x3b, att2, att3);

    k_att<<<dim3(N1 / 128, N1 / 128, BATCH), 256, 0, stream>>>(x1b, att2, att3, a1, a2, a3, attb);

    k_pv<<<dim3(N1 / 128, C1 / 128, BATCH), 256, 0, stream>>>(attb, x1t, x1b, (float*)d_out);
}